// Round 1
// baseline (695.848 us; speedup 1.0000x reference)
//
#include <hip/hip_runtime.h>
#include <hip/hip_bf16.h>
#include <cstdint>
#include <cstddef>

#define NN 50000
#define NE 800000
#define DD 128

typedef __attribute__((ext_vector_type(8))) short short8;
typedef __attribute__((ext_vector_type(4))) float f32x4;

__device__ __forceinline__ unsigned short f2bf(float f) {
  unsigned u = __float_as_uint(f);
  u = (u + 0x7FFFu + ((u >> 16) & 1u)) >> 16;
  return (unsigned short)u;
}

__device__ __forceinline__ short8 zero8() {
  short8 v;
#pragma unroll
  for (int j = 0; j < 8; ++j) v[j] = 0;
  return v;
}

// Convert 4 weight matrices [k][col] f32 -> transposed bf16 [col][k]
__global__ void k_prep(const float* __restrict__ Ws1, const float* __restrict__ Wr,
                       const float* __restrict__ Wm, const float* __restrict__ We,
                       unsigned short* __restrict__ Wt) {
  int i = blockIdx.x * blockDim.x + threadIdx.x;
  for (int idx = i; idx < 4 * DD * DD; idx += gridDim.x * blockDim.x) {
    int m = idx >> 14, r = idx & 16383, col = r >> 7, k = r & 127;
    const float* src = (m == 0) ? Ws1 : (m == 1) ? Wr : (m == 2) ? Wm : We;
    Wt[idx] = f2bf(src[k * DD + col]);
  }
}

// Stage one 128x128 bf16 weight matrix ([col][k] layout) into LDS with XOR swizzle.
__device__ __forceinline__ void stage_w(const unsigned short* __restrict__ Wt,
                                        uint4* __restrict__ ldsW4, int tid) {
#pragma unroll
  for (int c = 0; c < 8; ++c) {
    int ci = tid * 8 + c;           // 2048 chunks of 16B
    int lin = ci << 4;              // byte offset in linear [col][k] bf16
    int col = lin >> 8;             // 256 B per col-row
    int within = lin & 255;
    int sw = within ^ ((col & 7) << 4);
    uint4 v = *(const uint4*)((const char*)Wt + lin);
    *(uint4*)((char*)ldsW4 + (col << 8) + sw) = v;
  }
}

__device__ __forceinline__ short8 read_b(const char* __restrict__ ldsW, int col, int k0) {
  int byte = (col << 8) + (((k0 << 1)) ^ ((col & 7) << 4));
  return *(const short8*)(ldsW + byte);
}

__device__ __forceinline__ short8 load_a8(const float* __restrict__ p) {
  f32x4 f0 = *(const f32x4*)p;
  f32x4 f1 = *(const f32x4*)(p + 4);
  short8 t;
#pragma unroll
  for (int j = 0; j < 4; ++j) t[j] = f2bf(f0[j]);
#pragma unroll
  for (int j = 0; j < 4; ++j) t[4 + j] = f2bf(f1[j]);
  return t;
}

// P_m = nodes @ W_m + b_m for m in {s1, r, m}. Block: 128 rows x 128 cols, 4 waves (2x2).
__global__ __launch_bounds__(256) void k_nodeproj(
    const float* __restrict__ nodes, const unsigned short* __restrict__ Wt,
    const float* __restrict__ b_s1, const float* __restrict__ b_r, const float* __restrict__ b_m,
    float* __restrict__ P1, float* __restrict__ Pr, float* __restrict__ Pm) {
  __shared__ uint4 ldsW4[2048];
  int m = blockIdx.y;
  const unsigned short* W = Wt + m * 16384;
  const float* bias = (m == 0) ? b_s1 : (m == 1) ? b_r : b_m;
  float* P = (m == 0) ? P1 : (m == 1) ? Pr : Pm;
  int tid = threadIdx.x;
  stage_w(W, ldsW4, tid);
  __syncthreads();
  const char* ldsW = (const char*)ldsW4;
  int wid = tid >> 6, l = tid & 63;
  int wr = wid >> 1, wc = wid & 1;
  int rbase = blockIdx.x * 128 + wr * 64;
  int cbase = wc * 64;
  int lmod = l & 15, ldiv = l >> 4;

  f32x4 acc[4][4] = {};
#pragma unroll
  for (int kk = 0; kk < 4; ++kk) {
    int k0 = kk * 32 + ldiv * 8;
    short8 a[4];
#pragma unroll
    for (int rb = 0; rb < 4; ++rb) {
      int row = rbase + rb * 16 + lmod;
      a[rb] = (row < NN) ? load_a8(nodes + (size_t)row * DD + k0) : zero8();
    }
#pragma unroll
    for (int cb = 0; cb < 4; ++cb) {
      short8 b = read_b(ldsW, cbase + cb * 16 + lmod, k0);
#pragma unroll
      for (int rb = 0; rb < 4; ++rb)
        acc[rb][cb] = __builtin_amdgcn_mfma_f32_16x16x32_bf16(a[rb], b, acc[rb][cb], 0, 0, 0);
    }
  }
#pragma unroll
  for (int cb = 0; cb < 4; ++cb) {
    int col = cbase + cb * 16 + lmod;
    float bv = bias[col];
#pragma unroll
    for (int rb = 0; rb < 4; ++rb) {
#pragma unroll
      for (int r = 0; r < 4; ++r) {
        int row = rbase + rb * 16 + ldiv * 4 + r;
        if (row < NN) P[(size_t)row * DD + col] = acc[rb][cb][r] + bv;
      }
    }
  }
}

// edges_new = edges@W_e + b_e + P1[senders] + Pr[receivers]; att = leaky_relu(edges_new@W_att + b_att)
__global__ __launch_bounds__(256) void k_edge(
    const float* __restrict__ edges, const int* __restrict__ senders,
    const int* __restrict__ receivers, const unsigned short* __restrict__ WtE,
    const float* __restrict__ b_e, const float* __restrict__ P1, const float* __restrict__ Pr,
    const float* __restrict__ W_att, const float* __restrict__ b_att,
    float* __restrict__ out_edges, float* __restrict__ attb) {
  __shared__ uint4 ldsW4[2048];
  __shared__ float attpart[128][2];
  int tid = threadIdx.x;
  stage_w(WtE, ldsW4, tid);
  __syncthreads();
  const char* ldsW = (const char*)ldsW4;
  int wid = tid >> 6, l = tid & 63;
  int wr = wid >> 1, wc = wid & 1;
  int rbase = blockIdx.x * 128 + wr * 64;
  int cbase = wc * 64;
  int lmod = l & 15, ldiv = l >> 4;

  f32x4 acc[4][4] = {};
#pragma unroll
  for (int kk = 0; kk < 4; ++kk) {
    int k0 = kk * 32 + ldiv * 8;
    short8 a[4];
#pragma unroll
    for (int rb = 0; rb < 4; ++rb) {
      int row = rbase + rb * 16 + lmod;
      a[rb] = load_a8(edges + (size_t)row * DD + k0);
    }
#pragma unroll
    for (int cb = 0; cb < 4; ++cb) {
      short8 b = read_b(ldsW, cbase + cb * 16 + lmod, k0);
#pragma unroll
      for (int rb = 0; rb < 4; ++rb)
        acc[rb][cb] = __builtin_amdgcn_mfma_f32_16x16x32_bf16(a[rb], b, acc[rb][cb], 0, 0, 0);
    }
  }

  float wat[4], bev[4];
#pragma unroll
  for (int cb = 0; cb < 4; ++cb) {
    int col = cbase + cb * 16 + lmod;
    wat[cb] = W_att[col];
    bev[cb] = b_e[col];
  }
#pragma unroll
  for (int rb = 0; rb < 4; ++rb) {
#pragma unroll
    for (int r = 0; r < 4; ++r) {
      int lrow = wr * 64 + rb * 16 + ldiv * 4 + r;
      int e = blockIdx.x * 128 + lrow;
      int s = senders[e], rc = receivers[e];
      const float* p1 = P1 + (size_t)s * DD;
      const float* pr = Pr + (size_t)rc * DD;
      float* oe = out_edges + (size_t)e * DD;
      float part = 0.f;
#pragma unroll
      for (int cb = 0; cb < 4; ++cb) {
        int col = cbase + cb * 16 + lmod;
        float v = acc[rb][cb][r] + bev[cb] + p1[col] + pr[col];
        oe[col] = v;
        part += v * wat[cb];
      }
      part += __shfl_xor(part, 1);
      part += __shfl_xor(part, 2);
      part += __shfl_xor(part, 4);
      part += __shfl_xor(part, 8);
      if (lmod == 0) attpart[lrow][wc] = part;
    }
  }
  __syncthreads();
  if (tid < 128) {
    float av = attpart[tid][0] + attpart[tid][1] + b_att[0];
    av = (av >= 0.f) ? av : 0.01f * av;
    attb[blockIdx.x * 128 + tid] = av;
  }
}

__global__ void k_hist(const int* __restrict__ receivers, int* __restrict__ cnt) {
  int e = blockIdx.x * 256 + threadIdx.x;
  if (e < NE) atomicAdd(&cnt[receivers[e]], 1);
}

__global__ void k_scan(const int* __restrict__ cnt, int* __restrict__ offs) {
  __shared__ int sd[1024];
  __shared__ int sbase;
  int t = threadIdx.x;
  if (t == 0) sbase = 0;
  __syncthreads();
  for (int chunk = 0; chunk < NN; chunk += 1024) {
    int i = chunk + t;
    int v = (i < NN) ? cnt[i] : 0;
    sd[t] = v;
    __syncthreads();
    for (int d = 1; d < 1024; d <<= 1) {
      int add = (t >= d) ? sd[t - d] : 0;
      __syncthreads();
      sd[t] += add;
      __syncthreads();
    }
    int incl = sd[t];
    int base = sbase;
    if (i < NN) offs[i + 1] = base + incl;
    __syncthreads();
    if (t == 1023) sbase = base + sd[1023];
    __syncthreads();
  }
  if (t == 0) offs[0] = 0;
}

__global__ void k_fill(const int* __restrict__ receivers, const int* __restrict__ offs,
                       int* __restrict__ cursor, int* __restrict__ eidx) {
  int e = blockIdx.x * 256 + threadIdx.x;
  if (e < NE) {
    int rc = receivers[e];
    int pos = offs[rc] + atomicAdd(&cursor[rc], 1);
    eidx[pos] = e;
  }
}

// Per-node: softmax over incoming edges, weighted sum of Pm[senders]. One wave per node.
__global__ __launch_bounds__(256) void k_node(
    const int* __restrict__ offs, const int* __restrict__ eidx,
    const int* __restrict__ senders, const float* __restrict__ attb,
    const float* __restrict__ Pm, float* __restrict__ out_nodes) {
  int wid = threadIdx.x >> 6, l = threadIdx.x & 63;
  int n = blockIdx.x * 4 + wid;
  if (n >= NN) return;
  int start = offs[n], end = offs[n + 1];
  float m = -3.4e38f;
  for (int i = start; i < end; ++i) m = fmaxf(m, attb[eidx[i]]);
  float denom = 0.f;
  float ax = 0.f, ay = 0.f;
  for (int i = start; i < end; ++i) {
    int e = eidx[i];
    float w = expf(attb[e] - m);
    denom += w;
    const float2* pm = (const float2*)(Pm + (size_t)senders[e] * DD);
    float2 v = pm[l];
    ax += w * v.x;
    ay += w * v.y;
  }
  float2 o = {0.f, 0.f};
  if (end > start) {
    float inv = 1.f / denom;
    o.x = ax * inv;
    o.y = ay * inv;
  }
  *(float2*)(out_nodes + (size_t)n * DD + l * 2) = o;
}

extern "C" void kernel_launch(void* const* d_in, const int* in_sizes, int n_in,
                              void* d_out, int out_size, void* d_ws, size_t ws_size,
                              hipStream_t stream) {
  (void)in_sizes; (void)n_in; (void)out_size; (void)ws_size;
  const float* nodes = (const float*)d_in[0];
  const float* edges = (const float*)d_in[1];
  const int* senders = (const int*)d_in[2];
  const int* receivers = (const int*)d_in[3];
  const float* W_s1 = (const float*)d_in[4];
  const float* b_s1 = (const float*)d_in[5];
  const float* W_r = (const float*)d_in[6];
  const float* b_r = (const float*)d_in[7];
  const float* W_e = (const float*)d_in[8];
  const float* b_e = (const float*)d_in[9];
  const float* W_att = (const float*)d_in[10];
  const float* b_att = (const float*)d_in[11];
  const float* W_m = (const float*)d_in[12];
  const float* b_m = (const float*)d_in[13];

  float* out_nodes = (float*)d_out;
  float* out_edges = out_nodes + (size_t)NN * DD;

  char* w = (char*)d_ws;
  unsigned short* Wt = (unsigned short*)w; w += (size_t)4 * DD * DD * 2;   // 128 KB
  float* P1 = (float*)w; w += (size_t)NN * DD * 4;
  float* Pr = (float*)w; w += (size_t)NN * DD * 4;
  float* Pm = (float*)w; w += (size_t)NN * DD * 4;
  float* attb = (float*)w; w += (size_t)NE * 4;
  int* eidx = (int*)w; w += (size_t)NE * 4;
  int* cnt = (int*)w; w += (size_t)NN * 4;
  int* cursor = (int*)w; w += (size_t)NN * 4;
  int* offs = (int*)w; w += (size_t)(NN + 1) * 4;

  hipMemsetAsync(cnt, 0, (size_t)NN * 8, stream);  // cnt + cursor (contiguous)

  k_prep<<<64, 256, 0, stream>>>(W_s1, W_r, W_m, W_e, Wt);
  k_nodeproj<<<dim3(391, 3), 256, 0, stream>>>(nodes, Wt, b_s1, b_r, b_m, P1, Pr, Pm);
  k_edge<<<NE / 128, 256, 0, stream>>>(edges, senders, receivers, Wt + 3 * 16384, b_e,
                                       P1, Pr, W_att, b_att, out_edges, attb);
  k_hist<<<(NE + 255) / 256, 256, 0, stream>>>(receivers, cnt);
  k_scan<<<1, 1024, 0, stream>>>(cnt, offs);
  k_fill<<<(NE + 255) / 256, 256, 0, stream>>>(receivers, offs, cursor, eidx);
  k_node<<<NN / 4, 256, 0, stream>>>(offs, eidx, senders, attb, Pm, out_nodes);
}

// Round 2
// 621.327 us; speedup vs baseline: 1.1199x; 1.1199x over previous
//
#include <hip/hip_runtime.h>
#include <hip/hip_bf16.h>
#include <cstdint>
#include <cstddef>

#define NN 50000
#define NE 800000
#define DD 128

typedef __attribute__((ext_vector_type(8))) short short8;
typedef __attribute__((ext_vector_type(4))) float f32x4;

__device__ __forceinline__ unsigned short f2bf(float f) {
  unsigned u = __float_as_uint(f);
  u = (u + 0x7FFFu + ((u >> 16) & 1u)) >> 16;
  return (unsigned short)u;
}

__device__ __forceinline__ short8 zero8() {
  short8 v;
#pragma unroll
  for (int j = 0; j < 8; ++j) v[j] = 0;
  return v;
}

// Convert 4 weight matrices [k][col] f32 -> transposed bf16 [col][k]
__global__ void k_prep(const float* __restrict__ Ws1, const float* __restrict__ Wr,
                       const float* __restrict__ Wm, const float* __restrict__ We,
                       unsigned short* __restrict__ Wt) {
  int i = blockIdx.x * blockDim.x + threadIdx.x;
  for (int idx = i; idx < 4 * DD * DD; idx += gridDim.x * blockDim.x) {
    int m = idx >> 14, r = idx & 16383, col = r >> 7, k = r & 127;
    const float* src = (m == 0) ? Ws1 : (m == 1) ? Wr : (m == 2) ? Wm : We;
    Wt[idx] = f2bf(src[k * DD + col]);
  }
}

// Stage one 128x128 bf16 weight matrix ([col][k] layout) into LDS with XOR swizzle.
__device__ __forceinline__ void stage_w(const unsigned short* __restrict__ Wt,
                                        uint4* __restrict__ ldsW4, int tid) {
#pragma unroll
  for (int c = 0; c < 8; ++c) {
    int ci = tid * 8 + c;           // 2048 chunks of 16B
    int lin = ci << 4;              // byte offset in linear [col][k] bf16
    int col = lin >> 8;             // 256 B per col-row
    int within = lin & 255;
    int sw = within ^ ((col & 7) << 4);
    uint4 v = *(const uint4*)((const char*)Wt + lin);
    *(uint4*)((char*)ldsW4 + (col << 8) + sw) = v;
  }
}

__device__ __forceinline__ short8 read_w(const char* __restrict__ ldsW, int col, int k0) {
  int byte = (col << 8) + (((k0 << 1)) ^ ((col & 7) << 4));
  return *(const short8*)(ldsW + byte);
}

__device__ __forceinline__ short8 load_a8(const float* __restrict__ p) {
  f32x4 f0 = *(const f32x4*)p;
  f32x4 f1 = *(const f32x4*)(p + 4);
  short8 t;
#pragma unroll
  for (int j = 0; j < 4; ++j) t[j] = f2bf(f0[j]);
#pragma unroll
  for (int j = 0; j < 4; ++j) t[4 + j] = f2bf(f1[j]);
  return t;
}

// Swapped-operand node projection: D[d][row] = W^T x nodes^T.
// Wave handles 16 node rows (lane&15 selects row), all 128 d.
__global__ __launch_bounds__(256) void k_nodeproj(
    const float* __restrict__ nodes, const unsigned short* __restrict__ Wt,
    const float* __restrict__ b_s1, const float* __restrict__ b_r, const float* __restrict__ b_m,
    float* __restrict__ P1, float* __restrict__ Pr, float* __restrict__ Pm) {
  __shared__ uint4 ldsW4[2048];
  int m = blockIdx.y;
  const float* bias = (m == 0) ? b_s1 : (m == 1) ? b_r : b_m;
  float* P = (m == 0) ? P1 : (m == 1) ? Pr : Pm;
  int tid = threadIdx.x;
  stage_w(Wt + m * 16384, ldsW4, tid);
  __syncthreads();
  const char* ldsW = (const char*)ldsW4;
  int wid = tid >> 6, l = tid & 63;
  int lmod = l & 15, ldiv = l >> 4;
  int row = blockIdx.x * 64 + wid * 16 + lmod;
  bool ok = row < NN;

  f32x4 acc[8] = {};
#pragma unroll
  for (int kk = 0; kk < 4; ++kk) {
    int k0 = kk * 32 + ldiv * 8;
    short8 b = ok ? load_a8(nodes + (size_t)row * DD + k0) : zero8();
#pragma unroll
    for (int rb = 0; rb < 8; ++rb) {
      short8 a = read_w(ldsW, rb * 16 + lmod, k0);
      acc[rb] = __builtin_amdgcn_mfma_f32_16x16x32_bf16(a, b, acc[rb], 0, 0, 0);
    }
  }
  if (ok) {
    float* Prow = P + (size_t)row * DD;
#pragma unroll
    for (int rb = 0; rb < 8; ++rb) {
      int d0 = rb * 16 + ldiv * 4;
      f32x4 bv = *(const f32x4*)(bias + d0);
      f32x4 v = acc[rb];
#pragma unroll
      for (int j = 0; j < 4; ++j) v[j] += bv[j];
      *(f32x4*)(Prow + d0) = v;
    }
  }
}

// Fused edge kernel (swapped orientation): lane owns one edge, 4-consecutive-d
// accum registers. float4 gathers/stores, in-wave attention reduce, fused hist.
__global__ __launch_bounds__(256) void k_edge(
    const float* __restrict__ edges, const int* __restrict__ senders,
    const int* __restrict__ receivers, const unsigned short* __restrict__ WtE,
    const float* __restrict__ b_e, const float* __restrict__ P1, const float* __restrict__ Pr,
    const float* __restrict__ W_att, const float* __restrict__ b_att,
    float* __restrict__ out_edges, float* __restrict__ attb, int* __restrict__ cnt) {
  __shared__ uint4 ldsW4[2048];
  int tid = threadIdx.x;
  stage_w(WtE, ldsW4, tid);
  __syncthreads();
  const char* ldsW = (const char*)ldsW4;
  int wid = tid >> 6, l = tid & 63;
  int lmod = l & 15, ldiv = l >> 4;
  int e = blockIdx.x * 64 + wid * 16 + lmod;

  f32x4 acc[8] = {};
#pragma unroll
  for (int kk = 0; kk < 4; ++kk) {
    int k0 = kk * 32 + ldiv * 8;
    short8 b = load_a8(edges + (size_t)e * DD + k0);
#pragma unroll
    for (int rb = 0; rb < 8; ++rb) {
      short8 a = read_w(ldsW, rb * 16 + lmod, k0);
      acc[rb] = __builtin_amdgcn_mfma_f32_16x16x32_bf16(a, b, acc[rb], 0, 0, 0);
    }
  }

  int s = senders[e], rc = receivers[e];
  const float* p1 = P1 + (size_t)s * DD;
  const float* pr = Pr + (size_t)rc * DD;
  float* oe = out_edges + (size_t)e * DD;
  float att = 0.f;
#pragma unroll
  for (int rb = 0; rb < 8; ++rb) {
    int d0 = rb * 16 + ldiv * 4;
    f32x4 g1 = *(const f32x4*)(p1 + d0);
    f32x4 gr = *(const f32x4*)(pr + d0);
    f32x4 be = *(const f32x4*)(b_e + d0);
    f32x4 wa = *(const f32x4*)(W_att + d0);
    f32x4 v = acc[rb];
#pragma unroll
    for (int j = 0; j < 4; ++j) {
      float x = v[j] + be[j] + g1[j] + gr[j];
      v[j] = x;
      att += x * wa[j];
    }
    *(f32x4*)(oe + d0) = v;
  }
  att += __shfl_xor(att, 16);
  att += __shfl_xor(att, 32);
  if (ldiv == 0) {
    float av = att + b_att[0];
    av = (av >= 0.f) ? av : 0.01f * av;
    attb[e] = av;
    atomicAdd(&cnt[rc], 1);
  }
}

// Single-block shfl-based scan: 4 elems/thread, 13 chunks of 4096.
__global__ __launch_bounds__(1024) void k_scan(const int* __restrict__ cnt,
                                               int* __restrict__ offs) {
  __shared__ int wsum[16];
  __shared__ int sbase;
  int t = threadIdx.x;
  int lane = t & 63, wid = t >> 6;
  if (t == 0) { sbase = 0; offs[0] = 0; }
  __syncthreads();
  for (int c = 0; c < 13; ++c) {
    int i0 = c * 4096 + t * 4;
    int v0 = 0, v1 = 0, v2 = 0, v3 = 0;
    if (i0 + 3 < NN) {
      int4 v = *(const int4*)(cnt + i0);
      v0 = v.x; v1 = v.y; v2 = v.z; v3 = v.w;
    } else {
      if (i0 + 0 < NN) v0 = cnt[i0 + 0];
      if (i0 + 1 < NN) v1 = cnt[i0 + 1];
      if (i0 + 2 < NN) v2 = cnt[i0 + 2];
      if (i0 + 3 < NN) v3 = cnt[i0 + 3];
    }
    int p1 = v0, p2 = p1 + v1, p3 = p2 + v2, p4 = p3 + v3;
    int x = p4;
#pragma unroll
    for (int d = 1; d < 64; d <<= 1) {
      int o = __shfl_up(x, d, 64);
      if (lane >= d) x += o;
    }
    if (lane == 63) wsum[wid] = x;
    int excl_lane = x - p4;
    __syncthreads();
    int wbase = 0, tot = 0;
#pragma unroll
    for (int w2 = 0; w2 < 16; ++w2) {
      int sv = wsum[w2];
      if (w2 < wid) wbase += sv;
      tot += sv;
    }
    int base = sbase + wbase + excl_lane;
    if (i0 + 0 < NN) offs[i0 + 1] = base + p1;
    if (i0 + 1 < NN) offs[i0 + 2] = base + p2;
    if (i0 + 2 < NN) offs[i0 + 3] = base + p3;
    if (i0 + 3 < NN) offs[i0 + 4] = base + p4;
    __syncthreads();
    if (t == 0) sbase += tot;
    __syncthreads();
  }
}

__global__ void k_fill(const int* __restrict__ receivers, const int* __restrict__ offs,
                       int* __restrict__ cursor, int* __restrict__ eidx) {
  int e = blockIdx.x * 256 + threadIdx.x;
  if (e < NE) {
    int rc = receivers[e];
    int pos = offs[rc] + atomicAdd(&cursor[rc], 1);
    eidx[pos] = e;
  }
}

// Per-node: softmax over incoming edges, weighted sum of Pm[senders]. One wave per node.
__global__ __launch_bounds__(256) void k_node(
    const int* __restrict__ offs, const int* __restrict__ eidx,
    const int* __restrict__ senders, const float* __restrict__ attb,
    const float* __restrict__ Pm, float* __restrict__ out_nodes) {
  int wid = threadIdx.x >> 6, l = threadIdx.x & 63;
  int n = blockIdx.x * 4 + wid;
  if (n >= NN) return;
  int start = offs[n], end = offs[n + 1];
  float m = -3.4e38f;
  for (int i = start; i < end; ++i) m = fmaxf(m, attb[eidx[i]]);
  float denom = 0.f;
  float ax = 0.f, ay = 0.f;
  for (int i = start; i < end; ++i) {
    int e = eidx[i];
    float w = __expf(attb[e] - m);
    denom += w;
    const float2* pm = (const float2*)(Pm + (size_t)senders[e] * DD);
    float2 v = pm[l];
    ax += w * v.x;
    ay += w * v.y;
  }
  float2 o = {0.f, 0.f};
  if (end > start) {
    float inv = 1.f / denom;
    o.x = ax * inv;
    o.y = ay * inv;
  }
  *(float2*)(out_nodes + (size_t)n * DD + l * 2) = o;
}

extern "C" void kernel_launch(void* const* d_in, const int* in_sizes, int n_in,
                              void* d_out, int out_size, void* d_ws, size_t ws_size,
                              hipStream_t stream) {
  (void)in_sizes; (void)n_in; (void)out_size; (void)ws_size;
  const float* nodes = (const float*)d_in[0];
  const float* edges = (const float*)d_in[1];
  const int* senders = (const int*)d_in[2];
  const int* receivers = (const int*)d_in[3];
  const float* W_s1 = (const float*)d_in[4];
  const float* b_s1 = (const float*)d_in[5];
  const float* W_r = (const float*)d_in[6];
  const float* b_r = (const float*)d_in[7];
  const float* W_e = (const float*)d_in[8];
  const float* b_e = (const float*)d_in[9];
  const float* W_att = (const float*)d_in[10];
  const float* b_att = (const float*)d_in[11];
  const float* W_m = (const float*)d_in[12];
  const float* b_m = (const float*)d_in[13];

  float* out_nodes = (float*)d_out;
  float* out_edges = out_nodes + (size_t)NN * DD;

  char* w = (char*)d_ws;
  unsigned short* Wt = (unsigned short*)w; w += (size_t)4 * DD * DD * 2;   // 128 KB
  float* P1 = (float*)w; w += (size_t)NN * DD * 4;
  float* Pr = (float*)w; w += (size_t)NN * DD * 4;
  float* Pm = (float*)w; w += (size_t)NN * DD * 4;
  float* attb = (float*)w; w += (size_t)NE * 4;
  int* eidx = (int*)w; w += (size_t)NE * 4;
  int* cnt = (int*)w; w += (size_t)NN * 4;
  int* cursor = (int*)w; w += (size_t)NN * 4;
  int* offs = (int*)w; w += (size_t)(NN + 1) * 4;

  hipMemsetAsync(cnt, 0, (size_t)NN * 8, stream);  // cnt + cursor (contiguous)

  k_prep<<<64, 256, 0, stream>>>(W_s1, W_r, W_m, W_e, Wt);
  k_nodeproj<<<dim3(782, 3), 256, 0, stream>>>(nodes, Wt, b_s1, b_r, b_m, P1, Pr, Pm);
  k_edge<<<NE / 64, 256, 0, stream>>>(edges, senders, receivers, Wt + 3 * 16384, b_e,
                                      P1, Pr, W_att, b_att, out_edges, attb, cnt);
  k_scan<<<1, 1024, 0, stream>>>(cnt, offs);
  k_fill<<<(NE + 255) / 256, 256, 0, stream>>>(receivers, offs, cursor, eidx);
  k_node<<<NN / 4, 256, 0, stream>>>(offs, eidx, senders, attb, Pm, out_nodes);
}